// Round 8
// baseline (105.284 us; speedup 1.0000x reference)
//
#include <hip/hip_runtime.h>

#define N 8192
#define Dk 128
#define NC 1024   // class ids are in [0,1000); padded to 1024
#define EPSC 1e-6f
#define MARGIN 0.2f

typedef __attribute__((ext_vector_type(8))) short bf16x8;
typedef __attribute__((ext_vector_type(4))) float f32x4;

__device__ __forceinline__ unsigned short f2bf(float f) {
    unsigned u = __float_as_uint(f);
    u = (u + 0x7FFFu + ((u >> 16) & 1u)) >> 16;  // RNE fp32->bf16
    return (unsigned short)u;
}

// ---- sort pipeline (tiny kernels) ----
__global__ void hist_kernel(const int* __restrict__ tgt, int* __restrict__ hist) {
    int i = blockIdx.x * 256 + threadIdx.x;
    atomicAdd(&hist[tgt[i]], 1);
}

// exclusive scan of hist[0..1023] -> pref; also cursor = pref
__global__ void scan_kernel(const int* __restrict__ hist, int* __restrict__ pref,
                            int* __restrict__ cursor) {
    __shared__ int tmp[NC];
    int t = threadIdx.x;
    int h = hist[t];
    tmp[t] = h;
    __syncthreads();
#pragma unroll
    for (int off = 1; off < NC; off <<= 1) {
        int v = (t >= off) ? tmp[t - off] : 0;
        __syncthreads();
        tmp[t] += v;
        __syncthreads();
    }
    int ex = tmp[t] - h;
    pref[t] = ex;
    cursor[t] = ex;
}

// perm[pos] = original row; band[pos] = [classStart, classEnd); cls[pos] = class
__global__ void scatter_kernel(const int* __restrict__ tgt, const int* __restrict__ pref,
                               const int* __restrict__ hist, int* __restrict__ cursor,
                               int* __restrict__ perm, uint2* __restrict__ band,
                               int* __restrict__ cls) {
    int i = blockIdx.x * 256 + threadIdx.x;
    int c = tgt[i];
    int pos = atomicAdd(&cursor[c], 1);
    perm[pos] = i;
    uint2 b;
    b.x = (unsigned)pref[c];
    b.y = (unsigned)(pref[c] + hist[c]);
    band[pos] = b;
    cls[pos] = c;
}

// Kernel A: gather x[perm[k]] -> MFMA-fragment pack at permuted index k,
// P[k], QT[k] = (-Q/2, class). Frag uint4 F(rt,kk,lane)=(rt*4+kk)*64+lane.
__global__ void prep_kernel(const float* __restrict__ x, const int* __restrict__ perm,
                            const int* __restrict__ cls,
                            uint4* __restrict__ Frag, uint2* __restrict__ QT,
                            float* __restrict__ P) {
    int wv = blockIdx.x * 4 + (threadIdx.x >> 6);
    int lane = threadIdx.x & 63;
    int k = wv * 4 + (lane >> 4);  // permuted row
    int c = lane & 15;
    int orig = perm[k];
    const float4* x4 = reinterpret_cast<const float4*>(x);
    float4 v0 = x4[orig * 32 + c * 2];
    float4 v1 = x4[orig * 32 + c * 2 + 1];
    float sq = v0.x * v0.x + v0.y * v0.y + v0.z * v0.z + v0.w * v0.w +
               v1.x * v1.x + v1.y * v1.y + v1.z * v1.z + v1.w * v1.w;
    float s = v0.x + v0.y + v0.z + v0.w + v1.x + v1.y + v1.z + v1.w;
    ushort4 lo, hi;
    lo.x = f2bf(v0.x); lo.y = f2bf(v0.y); lo.z = f2bf(v0.z); lo.w = f2bf(v0.w);
    hi.x = f2bf(v1.x); hi.y = f2bf(v1.y); hi.z = f2bf(v1.z); hi.w = f2bf(v1.w);
    uint4 pk;
    pk.x = (unsigned)lo.x | ((unsigned)lo.y << 16);
    pk.y = (unsigned)lo.z | ((unsigned)lo.w << 16);
    pk.z = (unsigned)hi.x | ((unsigned)hi.y << 16);
    pk.w = (unsigned)hi.z | ((unsigned)hi.w << 16);
    Frag[((k >> 4) * 4 + (c >> 2)) * 64 + (c & 3) * 16 + (k & 15)] = pk;
#pragma unroll
    for (int m = 1; m <= 8; m <<= 1) {
        sq += __shfl_xor(sq, m);
        s += __shfl_xor(s, m);
    }
    if (c == 0) {
        P[k] = sq - 2.0f * EPSC * s;
        float Qj = sq + 2.0f * EPSC * s + (float)Dk * EPSC * EPSC;
        uint2 qt;
        qt.x = __float_as_uint(-0.5f * Qj);
        qt.y = (unsigned)cls[k];
        QT[k] = qt;
    }
}

#define LOADB(Bb, qq, t)                       \
    do {                                       \
        const int jt_ = jt0 + (t);             \
        Bb[0] = Fr[(jt_ * 4 + 0) * 64 + lane]; \
        Bb[1] = Fr[(jt_ * 4 + 1) * 64 + lane]; \
        Bb[2] = Fr[(jt_ * 4 + 2) * 64 + lane]; \
        Bb[3] = Fr[(jt_ * 4 + 3) * 64 + lane]; \
        qq = QT[jt_ * 16 + n];                 \
    } while (0)

// 16 MFMAs vs one j-tile; FAST epilogue = 16 fmax when the tile provably has no
// same-class pair (outside the sorted class band); exact masked path otherwise.
#define COMPUTE(Bb, qq, t)                                                            \
    do {                                                                              \
        const float Qv_ = __uint_as_float(qq.x); /* = -Q_j/2 */                       \
        f32x4 acc[4];                                                                 \
        acc[0] = Qv_; acc[1] = Qv_; acc[2] = Qv_; acc[3] = Qv_;                       \
        _Pragma("unroll")                                                             \
        for (int kk = 0; kk < 4; ++kk) {                                              \
            _Pragma("unroll")                                                         \
            for (int ti = 0; ti < 4; ++ti)                                            \
                acc[ti] = __builtin_amdgcn_mfma_f32_16x16x32_bf16(Af[ti][kk], Bb[kk], \
                                                                  acc[ti], 0, 0, 0);  \
        }                                                                             \
        const int jc_ = (jt0 + (t)) * 16;                                             \
        if (jc_ < bHi && jc_ + 16 > bLo) { /* wave-uniform: tile may hold same */     \
            const int tv_ = (int)qq.y;                                                \
            _Pragma("unroll")                                                         \
            for (int ti = 0; ti < 4; ++ti) {                                          \
                f32x4 v = acc[ti];                                                    \
                int e0 = tv_ == tsl[4 * ti + 0];                                      \
                int e1 = tv_ == tsl[4 * ti + 1];                                      \
                int e2 = tv_ == tsl[4 * ti + 2];                                      \
                int e3 = tv_ == tsl[4 * ti + 3];                                      \
                hp[4 * ti + 0] = fminf(hp[4 * ti + 0], e0 ? v[0] : INFINITY);         \
                hp[4 * ti + 1] = fminf(hp[4 * ti + 1], e1 ? v[1] : INFINITY);         \
                hp[4 * ti + 2] = fminf(hp[4 * ti + 2], e2 ? v[2] : INFINITY);         \
                hp[4 * ti + 3] = fminf(hp[4 * ti + 3], e3 ? v[3] : INFINITY);         \
                mn[4 * ti + 0] = fmaxf(mn[4 * ti + 0], e0 ? -INFINITY : v[0]);        \
                mn[4 * ti + 1] = fmaxf(mn[4 * ti + 1], e1 ? -INFINITY : v[1]);        \
                mn[4 * ti + 2] = fmaxf(mn[4 * ti + 2], e2 ? -INFINITY : v[2]);        \
                mn[4 * ti + 3] = fmaxf(mn[4 * ti + 3], e3 ? -INFINITY : v[3]);        \
            }                                                                         \
        } else { /* no same-class pair possible: pure unmasked max */                 \
            _Pragma("unroll")                                                         \
            for (int ti = 0; ti < 4; ++ti) {                                          \
                mn[4 * ti + 0] = fmaxf(mn[4 * ti + 0], acc[ti][0]);                   \
                mn[4 * ti + 1] = fmaxf(mn[4 * ti + 1], acc[ti][1]);                   \
                mn[4 * ti + 2] = fmaxf(mn[4 * ti + 2], acc[ti][2]);                   \
                mn[4 * ti + 3] = fmaxf(mn[4 * ti + 3], acc[ti][3]);                   \
            }                                                                         \
        }                                                                             \
    } while (0)

// Kernel B: NO LDS/barriers/atomics. All data in class-sorted permuted space.
// Grid = 128 i-groups x 8 j-groups; wave w streams 16 j-tiles, 3-deep register
// pipeline. acc init = -Q_j/2 => acc = dot - Q_j/2; d2 = P_i - 2*acc (monotone
// decreasing): hardest_pos = min acc over same, hardest_neg = max acc over diff.
__global__ __launch_bounds__(256, 2) void main_kernel(
        const uint4* __restrict__ Frag, const uint2* __restrict__ QT,
        const int* __restrict__ cls, const uint2* __restrict__ band,
        float* __restrict__ partHp, float* __restrict__ partMn) {
    const int w = threadIdx.x >> 6;
    const int lane = threadIdx.x & 63;
    const int n = lane & 15;
    const int q = lane >> 4;

    const int ig = (int)blockIdx.x >> 3;  // 0..127
    const int jg = (int)blockIdx.x & 7;   // 0..7
    const int rbase = ig * 64;
    const int jt0 = jg * 64 + w * 16;

    const bf16x8* Fr = reinterpret_cast<const bf16x8*>(Frag);

    // class band of this block's 64 rows (sorted => [start of first, end of last))
    const int bLo = (int)band[rbase].x;
    const int bHi = (int)band[rbase + 63].y;

    bf16x8 Af[4][4];
#pragma unroll
    for (int ti = 0; ti < 4; ++ti)
#pragma unroll
        for (int kk = 0; kk < 4; ++kk)
            Af[ti][kk] = Fr[((ig * 4 + ti) * 4 + kk) * 64 + lane];

    int tsl[16];
#pragma unroll
    for (int ti = 0; ti < 4; ++ti) {
        int4 t4 = *reinterpret_cast<const int4*>(&cls[rbase + 16 * ti + 4 * q]);
        tsl[4 * ti + 0] = t4.x;
        tsl[4 * ti + 1] = t4.y;
        tsl[4 * ti + 2] = t4.z;
        tsl[4 * ti + 3] = t4.w;
    }

    float hp[16], mn[16];
#pragma unroll
    for (int s = 0; s < 16; ++s) {
        hp[s] = INFINITY;
        mn[s] = -INFINITY;
    }

    bf16x8 B0[4], B1[4], B2[4];
    uint2 q0, q1, q2;
    LOADB(B0, q0, 0);
    LOADB(B1, q1, 1);
    LOADB(B2, q2, 2);
#pragma unroll
    for (int tt = 0; tt < 15; tt += 3) {
        COMPUTE(B0, q0, tt);
        if (tt + 3 < 16) LOADB(B0, q0, tt + 3);
        COMPUTE(B1, q1, tt + 1);
        if (tt + 4 < 16) LOADB(B1, q1, tt + 4);
        COMPUTE(B2, q2, tt + 2);
        if (tt + 5 < 16) LOADB(B2, q2, tt + 5);
    }
    COMPUTE(B0, q0, 15);

    // reduce across the 16 col-lanes; lanes n==0 commit rows 16ti+4q+r
#pragma unroll
    for (int m = 1; m <= 8; m <<= 1) {
#pragma unroll
        for (int s = 0; s < 16; ++s) {
            hp[s] = fminf(hp[s], __shfl_xor(hp[s], m));
            mn[s] = fmaxf(mn[s], __shfl_xor(mn[s], m));
        }
    }
    if (n == 0) {
        const int wg = jg * 4 + w;
#pragma unroll
        for (int ti = 0; ti < 4; ++ti)
#pragma unroll
            for (int r = 0; r < 4; ++r) {
                int i = rbase + 16 * ti + 4 * q + r;
                partHp[wg * N + i] = hp[4 * ti + r];
                partMn[wg * N + i] = mn[4 * ti + r];
            }
    }
}

// Kernel C: reduce 32 partials per (permuted) row, loss, mean (perm-invariant)
__global__ void finish_kernel(const float* __restrict__ P,
                              const float* __restrict__ partHp,
                              const float* __restrict__ partMn,
                              float* __restrict__ out) {
    int i = blockIdx.x * 256 + threadIdx.x;
    float hpm = INFINITY, mnm = -INFINITY;
#pragma unroll
    for (int wg = 0; wg < 32; ++wg) {
        hpm = fminf(hpm, partHp[wg * N + i]);
        mnm = fmaxf(mnm, partMn[wg * N + i]);
    }
    float Pi = P[i];
    float hp = sqrtf(fmaxf(fmaf(-2.0f, hpm, Pi), 0.0f));
    float hn = sqrtf(fmaxf(fmaf(-2.0f, mnm, Pi), 0.0f));
    float sum = fmaxf(hp - hn + MARGIN, 0.0f) * (1.0f / (float)N);
#pragma unroll
    for (int m = 32; m >= 1; m >>= 1) sum += __shfl_xor(sum, m);
    __shared__ float ws[4];
    int lane = threadIdx.x & 63, wv = threadIdx.x >> 6;
    if (lane == 0) ws[wv] = sum;
    __syncthreads();
    if (threadIdx.x == 0) atomicAdd(out, ws[0] + ws[1] + ws[2] + ws[3]);
}

extern "C" void kernel_launch(void* const* d_in, const int* in_sizes, int n_in,
                              void* d_out, int out_size, void* d_ws, size_t ws_size,
                              hipStream_t stream) {
    const float* x = (const float*)d_in[0];
    const int* tgt = (const int*)d_in[1];
    float* out = (float*)d_out;

    char* ws = (char*)d_ws;
    size_t off = 0;
    uint4* Frag = (uint4*)(ws + off); off += (size_t)N * Dk * 2;      // 2 MB
    uint2* QT = (uint2*)(ws + off); off += (size_t)N * 8;
    float* P = (float*)(ws + off); off += (size_t)N * 4;
    float* partHp = (float*)(ws + off); off += (size_t)32 * N * 4;    // 1 MB
    float* partMn = (float*)(ws + off); off += (size_t)32 * N * 4;    // 1 MB
    uint2* band = (uint2*)(ws + off); off += (size_t)N * 8;
    int* perm = (int*)(ws + off); off += (size_t)N * 4;
    int* cls = (int*)(ws + off); off += (size_t)N * 4;
    int* hist = (int*)(ws + off); off += NC * 4;
    int* pref = (int*)(ws + off); off += NC * 4;
    int* cursor = (int*)(ws + off); off += NC * 4;

    hipMemsetAsync(hist, 0, NC * 4, stream);
    hipMemsetAsync(d_out, 0, sizeof(float), stream);
    hist_kernel<<<N / 256, 256, 0, stream>>>(tgt, hist);
    scan_kernel<<<1, NC, 0, stream>>>(hist, pref, cursor);
    scatter_kernel<<<N / 256, 256, 0, stream>>>(tgt, pref, hist, cursor, perm, band, cls);
    prep_kernel<<<N / 16, 256, 0, stream>>>(x, perm, cls, Frag, QT, P);
    main_kernel<<<1024, 256, 0, stream>>>(Frag, QT, cls, band, partHp, partMn);
    finish_kernel<<<32, 256, 0, stream>>>(P, partHp, partMn, out);
}

// Round 9
// 102.737 us; speedup vs baseline: 1.0248x; 1.0248x over previous
//
#include <hip/hip_runtime.h>

#define N 8192
#define Dk 128
#define NC 1024   // class ids in [0,1000), padded
#define EPSC 1e-6f
#define MARGIN 0.2f

typedef __attribute__((ext_vector_type(8))) short bf16x8;
typedef __attribute__((ext_vector_type(4))) float f32x4;

__device__ __forceinline__ unsigned short f2bf(float f) {
    unsigned u = __float_as_uint(f);
    u = (u + 0x7FFFu + ((u >> 16) & 1u)) >> 16;  // RNE fp32->bf16
    return (unsigned short)u;
}

// ---- sort pipeline (verified R8) ----
__global__ void hist_kernel(const int* __restrict__ tgt, int* __restrict__ hist) {
    int i = blockIdx.x * 256 + threadIdx.x;
    atomicAdd(&hist[tgt[i]], 1);
}

__global__ void scan_kernel(const int* __restrict__ hist, int* __restrict__ pref,
                            int* __restrict__ cursor) {
    __shared__ int tmp[NC];
    int t = threadIdx.x;
    int h = hist[t];
    tmp[t] = h;
    __syncthreads();
#pragma unroll
    for (int off = 1; off < NC; off <<= 1) {
        int v = (t >= off) ? tmp[t - off] : 0;
        __syncthreads();
        tmp[t] += v;
        __syncthreads();
    }
    int ex = tmp[t] - h;
    pref[t] = ex;
    cursor[t] = ex;
}

__global__ void scatter_kernel(const int* __restrict__ tgt, const int* __restrict__ pref,
                               const int* __restrict__ hist, int* __restrict__ cursor,
                               int* __restrict__ perm, uint2* __restrict__ band,
                               int* __restrict__ cls) {
    int i = blockIdx.x * 256 + threadIdx.x;
    int c = tgt[i];
    int pos = atomicAdd(&cursor[c], 1);
    perm[pos] = i;
    uint2 b;
    b.x = (unsigned)pref[c];
    b.y = (unsigned)(pref[c] + hist[c]);
    band[pos] = b;
    cls[pos] = c;
}

// Kernel A: gather x[perm[k]] -> fragment pack (verified layout), P[k], Qh[k] = -Q/2
__global__ void prep_kernel(const float* __restrict__ x, const int* __restrict__ perm,
                            uint4* __restrict__ Frag, float* __restrict__ Qh,
                            float* __restrict__ P) {
    int wv = blockIdx.x * 4 + (threadIdx.x >> 6);
    int lane = threadIdx.x & 63;
    int k = wv * 4 + (lane >> 4);  // permuted row
    int c = lane & 15;
    int orig = perm[k];
    const float4* x4 = reinterpret_cast<const float4*>(x);
    float4 v0 = x4[orig * 32 + c * 2];
    float4 v1 = x4[orig * 32 + c * 2 + 1];
    float sq = v0.x * v0.x + v0.y * v0.y + v0.z * v0.z + v0.w * v0.w +
               v1.x * v1.x + v1.y * v1.y + v1.z * v1.z + v1.w * v1.w;
    float s = v0.x + v0.y + v0.z + v0.w + v1.x + v1.y + v1.z + v1.w;
    ushort4 lo, hi;
    lo.x = f2bf(v0.x); lo.y = f2bf(v0.y); lo.z = f2bf(v0.z); lo.w = f2bf(v0.w);
    hi.x = f2bf(v1.x); hi.y = f2bf(v1.y); hi.z = f2bf(v1.z); hi.w = f2bf(v1.w);
    uint4 pk;
    pk.x = (unsigned)lo.x | ((unsigned)lo.y << 16);
    pk.y = (unsigned)lo.z | ((unsigned)lo.w << 16);
    pk.z = (unsigned)hi.x | ((unsigned)hi.y << 16);
    pk.w = (unsigned)hi.z | ((unsigned)hi.w << 16);
    Frag[((k >> 4) * 4 + (c >> 2)) * 64 + (c & 3) * 16 + (k & 15)] = pk;
#pragma unroll
    for (int m = 1; m <= 8; m <<= 1) {
        sq += __shfl_xor(sq, m);
        s += __shfl_xor(s, m);
    }
    if (c == 0) {
        P[k] = sq - 2.0f * EPSC * s;
        Qh[k] = -0.5f * (sq + 2.0f * EPSC * s + (float)Dk * EPSC * EPSC);
    }
}

// load j-tile jt0+t: 4 coalesced 1KB fragment loads + its -Q/2 quad (lane's 4 j's)
#define LOADB(Bb, Qq, t)                                                \
    do {                                                                \
        const int jt_ = jt0 + (t);                                      \
        Bb[0] = Fr[(jt_ * 4 + 0) * 64 + lane];                          \
        Bb[1] = Fr[(jt_ * 4 + 1) * 64 + lane];                          \
        Bb[2] = Fr[(jt_ * 4 + 2) * 64 + lane];                          \
        Bb[3] = Fr[(jt_ * 4 + 3) * 64 + lane];                          \
        Qq = *reinterpret_cast<const f32x4*>(&Qh[jt_ * 16 + 4 * q]);    \
    } while (0)

// TRANSPOSED mfma: first operand = j-fragment, second = anchor-fragment.
// D[m][n] = sum_k x_{j_m}[k] * x_{i_n}[k]; lane: col n = anchor (lane&15),
// rows m = 4 j's (q*4+reg). C-init = -Q_j/2 quad => acc = dot - Q_j/2, FREE.
#define MFMA16(ACC, Bb, Qq)                                                           \
    do {                                                                              \
        _Pragma("unroll")                                                             \
        for (int ti = 0; ti < 4; ++ti) {                                              \
            ACC[ti] = __builtin_amdgcn_mfma_f32_16x16x32_bf16(Bb[0], Af[ti][0], Qq, 0, 0, 0); \
            ACC[ti] = __builtin_amdgcn_mfma_f32_16x16x32_bf16(Bb[1], Af[ti][1], ACC[ti], 0, 0, 0); \
            ACC[ti] = __builtin_amdgcn_mfma_f32_16x16x32_bf16(Bb[2], Af[ti][2], ACC[ti], 0, 0, 0); \
            ACC[ti] = __builtin_amdgcn_mfma_f32_16x16x32_bf16(Bb[3], Af[ti][3], ACC[ti], 0, 0, 0); \
        }                                                                             \
    } while (0)

// epilogue for tile t (deferred one step): fast path = 3 VALU per acc quad
#define EPILOGUE(ACC, t)                                                              \
    do {                                                                              \
        const int jc_ = (jt0 + (t)) * 16;                                             \
        if (jc_ < bHi && jc_ + 16 > bLo) { /* wave-uniform: may hold same-class */    \
            int4 cj = *reinterpret_cast<const int4*>(&cls[jc_ + 4 * q]);              \
            _Pragma("unroll")                                                         \
            for (int ti = 0; ti < 4; ++ti) {                                          \
                f32x4 v = ACC[ti];                                                    \
                int mc = myc[ti];                                                     \
                hp[ti] = fminf(hp[ti], cj.x == mc ? v[0] : INFINITY);                 \
                hp[ti] = fminf(hp[ti], cj.y == mc ? v[1] : INFINITY);                 \
                hp[ti] = fminf(hp[ti], cj.z == mc ? v[2] : INFINITY);                 \
                hp[ti] = fminf(hp[ti], cj.w == mc ? v[3] : INFINITY);                 \
                mn[ti] = fmaxf(mn[ti], cj.x == mc ? -INFINITY : v[0]);                \
                mn[ti] = fmaxf(mn[ti], cj.y == mc ? -INFINITY : v[1]);                \
                mn[ti] = fmaxf(mn[ti], cj.z == mc ? -INFINITY : v[2]);                \
                mn[ti] = fmaxf(mn[ti], cj.w == mc ? -INFINITY : v[3]);                \
            }                                                                         \
        } else { /* provably all-negative: tree-max, 3 VALU per quad */               \
            _Pragma("unroll")                                                         \
            for (int ti = 0; ti < 4; ++ti) {                                          \
                f32x4 v = ACC[ti];                                                    \
                mn[ti] = fmaxf(mn[ti], fmaxf(fmaxf(v[0], v[1]), fmaxf(v[2], v[3])));  \
            }                                                                         \
        }                                                                             \
    } while (0)

// MFMA(t) then EPILOGUE(t-1): epilogue VALU overlaps in-flight MFMAs (ping-pong acc)
#define STEP(t, ACCc, ACCp, Bc, Qc, Bp, Qp)   \
    do {                                      \
        MFMA16(ACCc, Bc, Qc);                 \
        if ((t) + 2 < 16) LOADB(Bp, Qp, (t) + 2); \
        if ((t) > 0) EPILOGUE(ACCp, (t) - 1); \
    } while (0)

// Kernel B: NO LDS/barriers/atomics. Grid = 32 ig x 32 jg; block = 256 anchors
// (4 waves stacked in i) x 256 j (16 tiles) -- all 4 waves SHARE the j-stream
// (L1 reuse). 3-buffer register prefetch + ping-pong acc. Sorted-band fast path.
__global__ __launch_bounds__(256, 2) void main_kernel(
        const uint4* __restrict__ Frag, const float* __restrict__ Qh,
        const int* __restrict__ cls, const uint2* __restrict__ band,
        float* __restrict__ partHp, float* __restrict__ partMn) {
    const int w = threadIdx.x >> 6;
    const int lane = threadIdx.x & 63;
    const int n = lane & 15;
    const int q = lane >> 4;

    const int ig = (int)blockIdx.x >> 5;   // 0..31
    const int jg = (int)blockIdx.x & 31;   // 0..31
    const int rw = ig * 256 + 64 * w;      // wave's 64 anchors
    const int jt0 = jg * 16;               // wave's 16 j-tiles (global tile units)

    const bf16x8* Fr = reinterpret_cast<const bf16x8*>(Frag);

    const int bLo = (int)band[rw].x;
    const int bHi = (int)band[rw + 63].y;

    // Persistent anchor fragments: 64 rows x K=128 (64 VGPRs)
    bf16x8 Af[4][4];
#pragma unroll
    for (int ti = 0; ti < 4; ++ti)
#pragma unroll
        for (int kk = 0; kk < 4; ++kk)
            Af[ti][kk] = Fr[(((rw >> 4) + ti) * 4 + kk) * 64 + lane];

    int myc[4];  // lane's anchor class per ti (anchor = rw + 16*ti + n)
#pragma unroll
    for (int ti = 0; ti < 4; ++ti) myc[ti] = cls[rw + 16 * ti + n];

    float hp[4], mn[4];
#pragma unroll
    for (int s = 0; s < 4; ++s) {
        hp[s] = INFINITY;   // min over same-class acc
        mn[s] = -INFINITY;  // max over diff-class acc
    }

    bf16x8 B0[4], B1[4], B2[4];
    f32x4 Q0, Q1, Q2;
    f32x4 accA[4], accB[4];

    LOADB(B0, Q0, 0);
    LOADB(B1, Q1, 1);
    STEP(0, accA, accB, B0, Q0, B2, Q2);
    STEP(1, accB, accA, B1, Q1, B0, Q0);
    STEP(2, accA, accB, B2, Q2, B1, Q1);
    STEP(3, accB, accA, B0, Q0, B2, Q2);
    STEP(4, accA, accB, B1, Q1, B0, Q0);
    STEP(5, accB, accA, B2, Q2, B1, Q1);
    STEP(6, accA, accB, B0, Q0, B2, Q2);
    STEP(7, accB, accA, B1, Q1, B0, Q0);
    STEP(8, accA, accB, B2, Q2, B1, Q1);
    STEP(9, accB, accA, B0, Q0, B2, Q2);
    STEP(10, accA, accB, B1, Q1, B0, Q0);
    STEP(11, accB, accA, B2, Q2, B1, Q1);
    STEP(12, accA, accB, B0, Q0, B2, Q2);
    STEP(13, accB, accA, B1, Q1, B0, Q0);
    STEP(14, accA, accB, B2, Q2, B1, Q1);
    STEP(15, accB, accA, B0, Q0, B2, Q2);
    EPILOGUE(accB, 15);

    // reduce across the 4 quads (lanes differing in bits 4,5); n preserved
#pragma unroll
    for (int m = 16; m <= 32; m <<= 1) {
#pragma unroll
        for (int s = 0; s < 4; ++s) {
            hp[s] = fminf(hp[s], __shfl_xor(hp[s], m));
            mn[s] = fmaxf(mn[s], __shfl_xor(mn[s], m));
        }
    }
    if (q == 0) {
#pragma unroll
        for (int ti = 0; ti < 4; ++ti) {
            int i = rw + 16 * ti + n;
            partHp[jg * N + i] = hp[ti];
            partMn[jg * N + i] = mn[ti];
        }
    }
}

// Kernel C: reduce 32 partials per (permuted) row, loss, mean (perm-invariant)
__global__ void finish_kernel(const float* __restrict__ P,
                              const float* __restrict__ partHp,
                              const float* __restrict__ partMn,
                              float* __restrict__ out) {
    int i = blockIdx.x * 256 + threadIdx.x;
    float hpm = INFINITY, mnm = -INFINITY;
#pragma unroll
    for (int wg = 0; wg < 32; ++wg) {
        hpm = fminf(hpm, partHp[wg * N + i]);
        mnm = fmaxf(mnm, partMn[wg * N + i]);
    }
    float Pi = P[i];
    float hp = sqrtf(fmaxf(fmaf(-2.0f, hpm, Pi), 0.0f));
    float hn = sqrtf(fmaxf(fmaf(-2.0f, mnm, Pi), 0.0f));
    float sum = fmaxf(hp - hn + MARGIN, 0.0f) * (1.0f / (float)N);
#pragma unroll
    for (int m = 32; m >= 1; m >>= 1) sum += __shfl_xor(sum, m);
    __shared__ float ws[4];
    int lane = threadIdx.x & 63, wv = threadIdx.x >> 6;
    if (lane == 0) ws[wv] = sum;
    __syncthreads();
    if (threadIdx.x == 0) atomicAdd(out, ws[0] + ws[1] + ws[2] + ws[3]);
}

extern "C" void kernel_launch(void* const* d_in, const int* in_sizes, int n_in,
                              void* d_out, int out_size, void* d_ws, size_t ws_size,
                              hipStream_t stream) {
    const float* x = (const float*)d_in[0];
    const int* tgt = (const int*)d_in[1];
    float* out = (float*)d_out;

    char* ws = (char*)d_ws;
    size_t off = 0;
    uint4* Frag = (uint4*)(ws + off); off += (size_t)N * Dk * 2;    // 2 MB
    float* Qh = (float*)(ws + off); off += (size_t)N * 4;
    float* P = (float*)(ws + off); off += (size_t)N * 4;
    float* partHp = (float*)(ws + off); off += (size_t)32 * N * 4;  // 1 MB
    float* partMn = (float*)(ws + off); off += (size_t)32 * N * 4;  // 1 MB
    uint2* band = (uint2*)(ws + off); off += (size_t)N * 8;
    int* perm = (int*)(ws + off); off += (size_t)N * 4;
    int* cls = (int*)(ws + off); off += (size_t)N * 4;
    int* hist = (int*)(ws + off); off += NC * 4;
    int* pref = (int*)(ws + off); off += NC * 4;
    int* cursor = (int*)(ws + off); off += NC * 4;

    hipMemsetAsync(hist, 0, NC * 4, stream);
    hipMemsetAsync(d_out, 0, sizeof(float), stream);
    hist_kernel<<<N / 256, 256, 0, stream>>>(tgt, hist);
    scan_kernel<<<1, NC, 0, stream>>>(hist, pref, cursor);
    scatter_kernel<<<N / 256, 256, 0, stream>>>(tgt, pref, hist, cursor, perm, band, cls);
    prep_kernel<<<N / 16, 256, 0, stream>>>(x, perm, Frag, Qh, P);
    main_kernel<<<1024, 256, 0, stream>>>(Frag, Qh, cls, band, partHp, partMn);
    finish_kernel<<<32, 256, 0, stream>>>(P, partHp, partMn, out);
}